// Round 13
// baseline (2477.071 us; speedup 1.0000x reference)
//
#include <hip/hip_runtime.h>
#include <math.h>

#define BB_ 32
#define TT_ 128
#define EE_ 64
#define HH_ 128
#define VV_ 32000
#define NMM 200      // matmul workgroups
#define NCELL 32     // cell workgroups (one per batch)
#define NWG (NMM + NCELL)
#define VW 160       // vocab rows per matmul wg (200*160 = 32000)
#define NREP 4       // h replicas (indexed by XCC_ID&3)

// ---- dynamic LDS layout (bytes) for matmul wgs ----
#define OFF_LW  0                   // float4[32 kcc][160 r] = 81920  fc_w slice
#define OFF_LHB 81920               // float[32 b][128 k]    = 16384  h tile
#define OFF_RDF 98304               // float[3*128]*41dw     = 62976  k-split reduce
// cell wgs overlay (same dynamic buffer, different CUs)
#define OFF_SG  0                   // float[512] gates
#define OFF_SH  2048                // float[128] h
#define OFF_TOK 2560                // int token broadcast
#define OFF_R64 2568                // u64[8] wave argmax partials
#define DYN_LDS 161280              // 157.5KB -> 1 wg/CU (160KB pool)

// ---- workspace layout (bytes) ----
// h-link: cell writes h to NREP XCD-local replicas (agent-atomic stores);
//         mm wgs read replica[XCC_ID&3] with PLAIN CACHED loads -> per-XCD L2
//         absorbs the fan-out with 4x fewer same-line LLC readers.
//         readiness via hsent sentinel replicas (x8, one line each).
// part-link: data IS the sentinel (packmax nonzero); reader-contiguous [s][b][widx].
#define WS_HQ    0                                          // f32[TT][NREP][BB][HH] = 8,388,608
#define WS_PART  (TT_*NREP*BB_*HH_*4)                       // u64[TT][BB][NMM] = 6,553,600
#define WS_HSENT (WS_PART + (size_t)TT_*BB_*NMM*8)          // u32[TT][8][32] = 131,072
#define WS_ZEND  (WS_HSENT + TT_*8*32*4)
#define WS_HENC  WS_ZEND                                    // f32[BB*HH]
#define WS_CENC  (WS_HENC + BB_*HH_*4)                      // f32[BB*HH]
#define WS_END   (WS_CENC + BB_*HH_*4)

__device__ __forceinline__ float rlane(float v, int l){
  return __int_as_float(__builtin_amdgcn_readlane(__float_as_int(v), l));
}
__device__ __forceinline__ float sigm(float x){ return 1.f / (1.f + expf(-x)); }

__device__ __forceinline__ unsigned xcc_id(){
  unsigned v;
  asm volatile("s_getreg_b32 %0, hwreg(HW_REG_XCC_ID)" : "=s"(v));
  return v & (NREP - 1);
}

__device__ __forceinline__ unsigned long long packmax(float v, int idx){
  unsigned u = __float_as_uint(v);
  u = (u & 0x80000000u) ? ~u : (u | 0x80000000u);   // monotone float->uint map
  return ((unsigned long long)u << 32) | (unsigned long long)(0xFFFFFFFFu - (unsigned)idx);
}

__device__ __forceinline__ unsigned aload32(const unsigned* p){
  return __hip_atomic_load(p, __ATOMIC_RELAXED, __HIP_MEMORY_SCOPE_AGENT);
}
__device__ __forceinline__ unsigned long long aload64(const unsigned long long* p){
  return __hip_atomic_load(p, __ATOMIC_RELAXED, __HIP_MEMORY_SCOPE_AGENT);
}
__device__ __forceinline__ void astore32(unsigned* p, unsigned v){
  __hip_atomic_store(p, v, __ATOMIC_RELAXED, __HIP_MEMORY_SCOPE_AGENT);
}
__device__ __forceinline__ void astore64(unsigned long long* p, unsigned long long v){
  __hip_atomic_store(p, v, __ATOMIC_RELAXED, __HIP_MEMORY_SCOPE_AGENT);
}

// Whh[row t]·h : 32 float4 L2-stream + readlane broadcasts. Runs in the mm window.
__device__ __forceinline__ float whh_dot(const float* wrow, float h0, float h1){
  const float4* hp = (const float4*)wrow;
  asm volatile("" : "+v"(hp));        // opaque: keep loads inside the loop iteration
  float b0 = 0.f, b1 = 0.f, b2 = 0.f, b3 = 0.f;
#pragma unroll
  for (int q = 0; q < 16; ++q){
    const float4 w = hp[q];
    b0 = fmaf(w.x, rlane(h0, q*4+0), b0);
    b1 = fmaf(w.y, rlane(h0, q*4+1), b1);
    b2 = fmaf(w.z, rlane(h0, q*4+2), b2);
    b3 = fmaf(w.w, rlane(h0, q*4+3), b3);
  }
#pragma unroll
  for (int q = 0; q < 16; ++q){
    const float4 w = hp[16+q];
    b0 = fmaf(w.x, rlane(h1, q*4+0), b0);
    b1 = fmaf(w.y, rlane(h1, q*4+1), b1);
    b2 = fmaf(w.z, rlane(h1, q*4+2), b2);
    b3 = fmaf(w.w, rlane(h1, q*4+3), b3);
  }
  return (b0 + b1) + (b2 + b3);
}

// register-resident full gate dot (encoder)
__device__ __forceinline__ float gate_dot_r(const float (&wih)[EE_], const float (&whh)[HH_],
                                            float bias, float xe, float h0, float h1){
  float a0 = bias, a1 = 0.f, a2 = 0.f, a3 = 0.f;
#pragma unroll
  for (int e = 0; e < EE_; e += 4){
    a0 = fmaf(wih[e+0], rlane(xe, e+0), a0);
    a1 = fmaf(wih[e+1], rlane(xe, e+1), a1);
    a2 = fmaf(wih[e+2], rlane(xe, e+2), a2);
    a3 = fmaf(wih[e+3], rlane(xe, e+3), a3);
  }
#pragma unroll
  for (int j = 0; j < 64; j += 4){
    a0 = fmaf(whh[j+0], rlane(h0, j+0), a0);
    a1 = fmaf(whh[j+1], rlane(h0, j+1), a1);
    a2 = fmaf(whh[j+2], rlane(h0, j+2), a2);
    a3 = fmaf(whh[j+3], rlane(h0, j+3), a3);
  }
#pragma unroll
  for (int j = 0; j < 64; j += 4){
    a0 = fmaf(whh[64+j+0], rlane(h1, j+0), a0);
    a1 = fmaf(whh[64+j+1], rlane(h1, j+1), a1);
    a2 = fmaf(whh[64+j+2], rlane(h1, j+2), a2);
    a3 = fmaf(whh[64+j+3], rlane(h1, j+3), a3);
  }
  return (a0 + a1) + (a2 + a3);
}

// ===================== encoder: 32 wgs (one per batch), no cross-wg deps =====================
__global__ __launch_bounds__(512)
void enc_kernel(const int* __restrict__ xt, const float* __restrict__ embed,
                const float* __restrict__ Wih, const float* __restrict__ Whh,
                const float* __restrict__ bv,
                float* __restrict__ h_out, float* __restrict__ c_out)
{
  const int b = blockIdx.x, t = threadIdx.x, lane = t & 63;
  __shared__ float sh[HH_];
  __shared__ float sg[4*HH_];
  float wih[EE_], whh[HH_];
#pragma unroll
  for (int e = 0; e < EE_; ++e) wih[e] = Wih[t*EE_ + e];
#pragma unroll
  for (int j = 0; j < HH_; ++j) whh[j] = Whh[t*HH_ + j];
  const float bias = bv[t];
  float c = 0.f, hv = 0.f;
  if (t < HH_) sh[t] = 0.f;
  __syncthreads();
#pragma unroll 1
  for (int s = 0; s < TT_; ++s){
    const int tok = xt[b*TT_ + s];
    const float xe = embed[tok*EE_ + lane];
    const float h0 = sh[lane], h1 = sh[64 + lane];
    const float g = gate_dot_r(wih, whh, bias, xe, h0, h1);
    __syncthreads();   // all sh reads done
    sg[t] = g;
    __syncthreads();
    if (t < HH_){
      const float gi = sg[t], gf = sg[128+t], gg = sg[256+t], go = sg[384+t];
      c = sigm(gf)*c + sigm(gi)*tanhf(gg);
      hv = sigm(go)*tanhf(c);
      sh[t] = hv;
    }
    __syncthreads();
  }
  if (t < HH_){ h_out[b*HH_ + t] = hv; c_out[b*HH_ + t] = c; }
}

// ===================== decoder: persistent, 32 cell wgs + 200 matmul wgs =====================
__global__ __launch_bounds__(512)
void dec_kernel(const float* __restrict__ embed,
                const float* __restrict__ dWih, const float* __restrict__ dWhh,
                const float* __restrict__ db,
                const float* __restrict__ fcw, const float* __restrict__ fcb,
                const float* __restrict__ h_enc, const float* __restrict__ c_enc,
                float* __restrict__ hq, unsigned long long* __restrict__ part,
                unsigned* __restrict__ hsent, float* __restrict__ out)
{
  extern __shared__ char smem[];
  const int t = threadIdx.x;
  const int wg = blockIdx.x;

  if (wg < NCELL){
    // ---------------- cell workgroup: owns batch b (pipelined gate) ----------------
    float* sg = (float*)(smem + OFF_SG);
    float* sh = (float*)(smem + OFF_SH);
    int* stok = (int*)(smem + OFF_TOK);
    unsigned long long* r64 = (unsigned long long*)(smem + OFF_R64);
    const int b = wg, lane = t & 63;
    const float bias = db[t];
    float wih[EE_];                       // x-part weights live in REGISTERS
#pragma unroll
    for (int e = 0; e < EE_; ++e) wih[e] = dWih[t*EE_ + e];
    float c = 0.f;
    if (t < HH_){ c = c_enc[b*HH_ + t]; sh[t] = h_enc[b*HH_ + t]; }
    int tok = 1; // SOS
    __syncthreads();
    // Whh·h for the first step (h_enc), off the critical chain
    float hacc = whh_dot(dWhh + t*HH_, sh[lane], sh[64 + lane]);
#pragma unroll 1
    for (int s = 0; s < TT_; ++s){
      // token-dependent part only: 64 reg-FMAs + one (prefetched) embed row
      const float xe = embed[tok*EE_ + lane];
      float a0 = bias + hacc, a1 = 0.f, a2 = 0.f, a3 = 0.f;
#pragma unroll
      for (int e = 0; e < EE_; e += 4){
        a0 = fmaf(wih[e+0], rlane(xe, e+0), a0);
        a1 = fmaf(wih[e+1], rlane(xe, e+1), a1);
        a2 = fmaf(wih[e+2], rlane(xe, e+2), a2);
        a3 = fmaf(wih[e+3], rlane(xe, e+3), a3);
      }
      sg[t] = (a0 + a1) + (a2 + a3);
      __syncthreads();
      if (t < HH_){
        const float gi = sg[t], gf = sg[128+t], gg = sg[256+t], go = sg[384+t];
        c = sigm(gf)*c + sigm(gi)*tanhf(gg);
        const float hv = sigm(go)*tanhf(c);
        sh[t] = hv;
        const unsigned hvb = __float_as_uint(hv);
#pragma unroll
        for (int r = 0; r < NREP; ++r)   // 4 XCD-local replicas, coalesced per replica
          __hip_atomic_store((unsigned*)&hq[(((size_t)s*NREP + r)*BB_ + b)*HH_ + t],
                             hvb, __ATOMIC_RELAXED, __HIP_MEMORY_SCOPE_AGENT);
      }
      __syncthreads();          // sh ready AND all waves' h stores drained (vmcnt0 at barrier)
      // bump all 8 sentinel REPLICAS in parallel (8 lanes -> 8 distinct lines)
      if (t < 8) astore32(&hsent[(s*8 + t)*32 + b], 1u);
      // overlapped with the mm window: Whh·h for the NEXT step
      const float hacc_n = whh_dot(dWhh + t*HH_, sh[lane], sh[64 + lane]);
      // busy-spin poll of this batch's 200 argmax partials (data IS the sentinel);
      // as each candidate arrives, touch its embed row -> winner is cache-hot.
      unsigned long long m = 0ull;
      if (t < NMM){
        const unsigned long long* pp = part + ((size_t)s*BB_ + b)*NMM + t;
        bool pf = false;
        for (;;){
          if (!m) m = aload64(pp);
          if (m && !pf){
            pf = true;
            const unsigned idx = 0xFFFFFFFFu - (unsigned)(m & 0xFFFFFFFFull);
            const float* er = embed + (size_t)idx*EE_;
            const float p0 = er[0], p1 = er[32];     // both 128B lines of the row
            asm volatile("" :: "v"(p0), "v"(p1));    // keep the touch loads alive
          }
          if (__all(m != 0)) break;
        }
      }
#pragma unroll
      for (int off = 32; off > 0; off >>= 1){
        const unsigned long long o = __shfl_xor(m, off);
        if (o > m) m = o;
      }
      if ((t & 63) == 0) r64[t >> 6] = m;
      __syncthreads();
      if (t == 0){
        unsigned long long best = r64[0];
#pragma unroll
        for (int w = 1; w < 8; ++w) if (r64[w] > best) best = r64[w];
        *stok = (int)(0xFFFFFFFFu - (unsigned)(best & 0xFFFFFFFFull));
      }
      __syncthreads();
      tok = *stok;
      hacc = hacc_n;
    }
  } else {
    // ---------------- matmul workgroup: vocab rows [v0, v0+VW) ----------------
    const int widx = wg - NCELL;
    const int v0 = widx * VW;
    float4* lw4 = (float4*)(smem + OFF_LW);   // [kcc][r]
    float*  lhb = (float*)(smem + OFF_LHB);   // [b][k], stride 128
    float*  rdf = (float*)(smem + OFF_RDF);
    const int ks = t >> 7;          // k-split quarter: k in [ks*32, ks*32+32)
    const int u  = t & 127;
    const int vg = u & 31;          // vocab lane; row v = v0 + vi*32 + vg
    const int bg = u >> 5;          // batch group (8 batches each)
    const unsigned myrep = xcc_id();          // XCD-local h replica index
    // stage fc_w slice into LDS once (reused for all 128 steps)
    for (int i = t; i < VW*HH_; i += 512){
      const int r = i >> 7, k = i & 127;
      ((float*)lw4)[((k >> 2)*VW + r)*4 + (k & 3)] = fcw[(size_t)(v0 + r)*HH_ + k];
    }
    float fb[5];
#pragma unroll
    for (int vi = 0; vi < 5; ++vi) fb[vi] = fcb[v0 + vi*32 + vg];
    __syncthreads();
#pragma unroll 1
    for (int s = 0; s < TT_; ++s){
      // busy-spin poll of THIS WG'S sentinel replica line (wave 0 only; 25 pollers/line)
      if (t < 64){
        unsigned v = (t < 32) ? 0u : 1u;
        const unsigned* sl = &hsent[(s*8 + (widx & 7))*32 + t];
        for (;;){
          if (!v) v = aload32(sl);
          if (__all(v != 0)) break;
        }
      }
      __syncthreads();
      // PLAIN cached, coalesced h stage from the XCD-LOCAL replica
      const float4* hsrc = (const float4*)(hq + ((size_t)s*NREP + myrep)*BB_*HH_);
#pragma unroll
      for (int i = t; i < BB_*HH_/4; i += 512){
        const float4 v = hsrc[i];
        const int bb = i >> 5, k4 = i & 31;
        *(float4*)&lhb[bb*HH_ + k4*4] = v;
      }
      __syncthreads();
      float acc[5][8];
#pragma unroll
      for (int vi = 0; vi < 5; ++vi)
#pragma unroll
        for (int bi = 0; bi < 8; ++bi) acc[vi][bi] = 0.f;
      const int kb = ks * 8;      // 8 float4-chunks (32 k) per ks
#pragma unroll
      for (int kc = 0; kc < 8; ++kc){
        const int kcc = kb + kc;
        float4 w[5];
#pragma unroll
        for (int vi = 0; vi < 5; ++vi) w[vi] = lw4[kcc*VW + vi*32 + vg];  // read ONCE per kc
#pragma unroll
        for (int bi = 0; bi < 8; ++bi){
          const float4 hb = *(const float4*)&lhb[(bg*8 + bi)*HH_ + kcc*4];  // broadcast read
#pragma unroll
          for (int vi = 0; vi < 5; ++vi)
            acc[vi][bi] = fmaf(w[vi].x,hb.x,fmaf(w[vi].y,hb.y,fmaf(w[vi].z,hb.z,fmaf(w[vi].w,hb.w,acc[vi][bi]))));
        }
      }
      // k-split reduce: ks=1..3 publish, ks=0 combines (stride-41 dwords)
      if (ks){
        float* dst = rdf + ((size_t)(ks-1)*128 + u)*41;
#pragma unroll
        for (int vi = 0; vi < 5; ++vi)
#pragma unroll
          for (int bi = 0; bi < 8; ++bi) dst[vi*8 + bi] = acc[vi][bi];
      }
      __syncthreads();
      if (ks == 0){
#pragma unroll
        for (int r = 0; r < 3; ++r){
          const float* src = rdf + ((size_t)r*128 + u)*41;
#pragma unroll
          for (int vi = 0; vi < 5; ++vi)
#pragma unroll
            for (int bi = 0; bi < 8; ++bi) acc[vi][bi] += src[vi*8 + bi];
        }
#pragma unroll
        for (int vi = 0; vi < 5; ++vi)
#pragma unroll
          for (int bi = 0; bi < 8; ++bi) acc[vi][bi] += fb[vi];
        // per-batch argmax over this wg's 160 rows -> ONE sentinel store per (wg,batch)
#pragma unroll
        for (int bi = 0; bi < 8; ++bi){
          unsigned long long best = 0ull;
#pragma unroll
          for (int vi = 0; vi < 5; ++vi){
            const unsigned long long pk = packmax(acc[vi][bi], v0 + vi*32 + vg);
            if (pk > best) best = pk;
          }
#pragma unroll
          for (int off = 16; off > 0; off >>= 1){
            const unsigned long long o = __shfl_xor(best, off);
            if (o > best) best = o;
          }
          if (vg == 0)
            astore64(&part[((size_t)s*BB_ + bg*8 + bi)*NMM + widx], best);
        }
        // logits after publication (nontemporal; drain during next poll window)
#pragma unroll
        for (int bi = 0; bi < 8; ++bi){
          float* orow = out + ((size_t)(bg*8 + bi)*TT_ + s)*(size_t)VV_ + v0;
#pragma unroll
          for (int vi = 0; vi < 5; ++vi)
            __builtin_nontemporal_store(acc[vi][bi], &orow[vi*32 + vg]);
        }
      }
    }
  }
}

extern "C" void kernel_launch(void* const* d_in, const int* in_sizes, int n_in,
                              void* d_out, int out_size, void* d_ws, size_t ws_size,
                              hipStream_t stream){
  (void)in_sizes; (void)n_in; (void)out_size; (void)ws_size;
  const int*   x     = (const int*)  d_in[0];
  const float* embed = (const float*)d_in[1];
  const float* eWih  = (const float*)d_in[2];
  const float* eWhh  = (const float*)d_in[3];
  const float* eb    = (const float*)d_in[4];
  const float* dWih  = (const float*)d_in[5];
  const float* dWhh  = (const float*)d_in[6];
  const float* db    = (const float*)d_in[7];
  const float* fcw   = (const float*)d_in[8];
  const float* fcb   = (const float*)d_in[9];
  float* out = (float*)d_out;
  char* ws = (char*)d_ws;
  float* hq = (float*)(ws + WS_HQ);
  unsigned long long* part = (unsigned long long*)(ws + WS_PART);
  unsigned* hsent = (unsigned*)(ws + WS_HSENT);
  float* h_enc = (float*)(ws + WS_HENC);
  float* c_enc = (float*)(ws + WS_CENC);

  // zero only the SENTINEL surfaces (part, hsent) each launch: hq is covered by
  // hsent readiness and needs no clearing. (graph node -> deterministic replays;
  // clears the harness 0xAA poison which would defeat the sentinels)
  (void)hipMemsetAsync(ws + WS_PART, 0, WS_ZEND - WS_PART, stream);
  // allow >64KB dynamic LDS (gfx950 has 160KB/CU); idempotent host-side call
  (void)hipFuncSetAttribute((const void*)dec_kernel, hipFuncAttributeMaxDynamicSharedMemorySize, DYN_LDS);

  enc_kernel<<<NCELL, 512, 0, stream>>>(x, embed, eWih, eWhh, eb, h_enc, c_enc);
  dec_kernel<<<NWG, 512, DYN_LDS, stream>>>(embed, dWih, dWhh, db, fcw, fcb,
                                            h_enc, c_enc, hq, part, hsent, out);
}

// Round 14
// 2127.152 us; speedup vs baseline: 1.1645x; 1.1645x over previous
//
#include <hip/hip_runtime.h>
#include <math.h>

#define BB_ 32
#define TT_ 128
#define EE_ 64
#define HH_ 128
#define VV_ 32000
#define NMM 200      // matmul workgroups
#define NCELL 32     // cell workgroups (one per batch)
#define NWG (NMM + NCELL)
#define VW 160       // vocab rows per matmul wg (200*160 = 32000)

// ---- dynamic LDS layout (bytes) for matmul wgs ----
#define OFF_LW  0                   // float4[32 kcc][160 r] = 81920  fc_w slice
#define OFF_LHB 81920               // float[32 b][128 k]    = 16384  h tile
#define OFF_RDF 98304               // float[3*128]*41dw     = 62976  k-split reduce
// cell wgs overlay (same dynamic buffer, different CUs)
#define OFF_SG  0                   // float[512] gates
#define OFF_SH  2048                // float[128] h
#define OFF_TOK 2560                // int token broadcast
#define OFF_R64 2568                // u64[8] wave argmax partials
#define DYN_LDS 161280              // 157.5KB -> 1 wg/CU (160KB pool)

// ---- workspace layout (bytes) ----
// h-link: agent-atomic u32 h stores -> LLC; per-batch sentinel REPLICATED x8
//         (one 128B line per replica; 25 pollers/line instead of 200);
//         readers use PLAIN CACHED loads for h (per-XCD L2 multicast).
// part-link: data IS the sentinel (packmax nonzero); reader-contiguous [s][b][widx].
#define WS_HQ    0                                          // f32[TT][BB][HH] = 2,097,152
#define WS_PART  (TT_*BB_*HH_*4)                            // u64[TT][BB][NMM] = 6,553,600
#define WS_HSENT (WS_PART + TT_*BB_*NMM*8)                  // u32[TT][8][32] = 131,072
#define WS_ZEND  (WS_HSENT + TT_*8*32*4)                    // zero [0, WS_ZEND) each launch
#define WS_HENC  WS_ZEND                                    // f32[BB*HH]
#define WS_CENC  (WS_HENC + BB_*HH_*4)                      // f32[BB*HH]
#define WS_END   (WS_CENC + BB_*HH_*4)

__device__ __forceinline__ float rlane(float v, int l){
  return __int_as_float(__builtin_amdgcn_readlane(__float_as_int(v), l));
}
__device__ __forceinline__ float sigm(float x){ return 1.f / (1.f + expf(-x)); }

__device__ __forceinline__ unsigned long long packmax(float v, int idx){
  unsigned u = __float_as_uint(v);
  u = (u & 0x80000000u) ? ~u : (u | 0x80000000u);   // monotone float->uint map
  return ((unsigned long long)u << 32) | (unsigned long long)(0xFFFFFFFFu - (unsigned)idx);
}

__device__ __forceinline__ unsigned aload32(const unsigned* p){
  return __hip_atomic_load(p, __ATOMIC_RELAXED, __HIP_MEMORY_SCOPE_AGENT);
}
__device__ __forceinline__ unsigned long long aload64(const unsigned long long* p){
  return __hip_atomic_load(p, __ATOMIC_RELAXED, __HIP_MEMORY_SCOPE_AGENT);
}
__device__ __forceinline__ void astore32(unsigned* p, unsigned v){
  __hip_atomic_store(p, v, __ATOMIC_RELAXED, __HIP_MEMORY_SCOPE_AGENT);
}
__device__ __forceinline__ void astore64(unsigned long long* p, unsigned long long v){
  __hip_atomic_store(p, v, __ATOMIC_RELAXED, __HIP_MEMORY_SCOPE_AGENT);
}

// Whh[row t]·h : 32 float4 L2-stream + readlane broadcasts. Runs in the mm window.
__device__ __forceinline__ float whh_dot(const float* wrow, float h0, float h1){
  const float4* hp = (const float4*)wrow;
  asm volatile("" : "+v"(hp));        // opaque: keep loads inside the loop iteration
  float b0 = 0.f, b1 = 0.f, b2 = 0.f, b3 = 0.f;
#pragma unroll
  for (int q = 0; q < 16; ++q){
    const float4 w = hp[q];
    b0 = fmaf(w.x, rlane(h0, q*4+0), b0);
    b1 = fmaf(w.y, rlane(h0, q*4+1), b1);
    b2 = fmaf(w.z, rlane(h0, q*4+2), b2);
    b3 = fmaf(w.w, rlane(h0, q*4+3), b3);
  }
#pragma unroll
  for (int q = 0; q < 16; ++q){
    const float4 w = hp[16+q];
    b0 = fmaf(w.x, rlane(h1, q*4+0), b0);
    b1 = fmaf(w.y, rlane(h1, q*4+1), b1);
    b2 = fmaf(w.z, rlane(h1, q*4+2), b2);
    b3 = fmaf(w.w, rlane(h1, q*4+3), b3);
  }
  return (b0 + b1) + (b2 + b3);
}

// register-resident full gate dot (encoder)
__device__ __forceinline__ float gate_dot_r(const float (&wih)[EE_], const float (&whh)[HH_],
                                            float bias, float xe, float h0, float h1){
  float a0 = bias, a1 = 0.f, a2 = 0.f, a3 = 0.f;
#pragma unroll
  for (int e = 0; e < EE_; e += 4){
    a0 = fmaf(wih[e+0], rlane(xe, e+0), a0);
    a1 = fmaf(wih[e+1], rlane(xe, e+1), a1);
    a2 = fmaf(wih[e+2], rlane(xe, e+2), a2);
    a3 = fmaf(wih[e+3], rlane(xe, e+3), a3);
  }
#pragma unroll
  for (int j = 0; j < 64; j += 4){
    a0 = fmaf(whh[j+0], rlane(h0, j+0), a0);
    a1 = fmaf(whh[j+1], rlane(h0, j+1), a1);
    a2 = fmaf(whh[j+2], rlane(h0, j+2), a2);
    a3 = fmaf(whh[j+3], rlane(h0, j+3), a3);
  }
#pragma unroll
  for (int j = 0; j < 64; j += 4){
    a0 = fmaf(whh[64+j+0], rlane(h1, j+0), a0);
    a1 = fmaf(whh[64+j+1], rlane(h1, j+1), a1);
    a2 = fmaf(whh[64+j+2], rlane(h1, j+2), a2);
    a3 = fmaf(whh[64+j+3], rlane(h1, j+3), a3);
  }
  return (a0 + a1) + (a2 + a3);
}

// ===================== encoder: 32 wgs (one per batch), no cross-wg deps =====================
__global__ __launch_bounds__(512)
void enc_kernel(const int* __restrict__ xt, const float* __restrict__ embed,
                const float* __restrict__ Wih, const float* __restrict__ Whh,
                const float* __restrict__ bv,
                float* __restrict__ h_out, float* __restrict__ c_out)
{
  const int b = blockIdx.x, t = threadIdx.x, lane = t & 63;
  __shared__ float sh[HH_];
  __shared__ float sg[4*HH_];
  float wih[EE_], whh[HH_];
#pragma unroll
  for (int e = 0; e < EE_; ++e) wih[e] = Wih[t*EE_ + e];
#pragma unroll
  for (int j = 0; j < HH_; ++j) whh[j] = Whh[t*HH_ + j];
  const float bias = bv[t];
  float c = 0.f, hv = 0.f;
  if (t < HH_) sh[t] = 0.f;
  __syncthreads();
#pragma unroll 1
  for (int s = 0; s < TT_; ++s){
    const int tok = xt[b*TT_ + s];
    const float xe = embed[tok*EE_ + lane];
    const float h0 = sh[lane], h1 = sh[64 + lane];
    const float g = gate_dot_r(wih, whh, bias, xe, h0, h1);
    __syncthreads();   // all sh reads done
    sg[t] = g;
    __syncthreads();
    if (t < HH_){
      const float gi = sg[t], gf = sg[128+t], gg = sg[256+t], go = sg[384+t];
      c = sigm(gf)*c + sigm(gi)*tanhf(gg);
      hv = sigm(go)*tanhf(c);
      sh[t] = hv;
    }
    __syncthreads();
  }
  if (t < HH_){ h_out[b*HH_ + t] = hv; c_out[b*HH_ + t] = c; }
}

// ===================== decoder: persistent, 32 cell wgs + 200 matmul wgs =====================
__global__ __launch_bounds__(512)
void dec_kernel(const float* __restrict__ embed,
                const float* __restrict__ dWih, const float* __restrict__ dWhh,
                const float* __restrict__ db,
                const float* __restrict__ fcw, const float* __restrict__ fcb,
                const float* __restrict__ h_enc, const float* __restrict__ c_enc,
                float* __restrict__ hq, unsigned long long* __restrict__ part,
                unsigned* __restrict__ hsent, float* __restrict__ out)
{
  extern __shared__ char smem[];
  const int t = threadIdx.x;
  const int wg = blockIdx.x;

  if (wg < NCELL){
    // ---------------- cell workgroup: owns batch b (pipelined gate) ----------------
    float* sg = (float*)(smem + OFF_SG);
    float* sh = (float*)(smem + OFF_SH);
    int* stok = (int*)(smem + OFF_TOK);
    unsigned long long* r64 = (unsigned long long*)(smem + OFF_R64);
    const int b = wg, lane = t & 63;
    const float bias = db[t];
    float wih[EE_];                       // x-part weights live in REGISTERS
#pragma unroll
    for (int e = 0; e < EE_; ++e) wih[e] = dWih[t*EE_ + e];
    float c = 0.f;
    if (t < HH_){ c = c_enc[b*HH_ + t]; sh[t] = h_enc[b*HH_ + t]; }
    int tok = 1; // SOS
    __syncthreads();
    // Whh·h for the first step (h_enc), off the critical chain
    float hacc = whh_dot(dWhh + t*HH_, sh[lane], sh[64 + lane]);
#pragma unroll 1
    for (int s = 0; s < TT_; ++s){
      // token-dependent part only: 64 reg-FMAs + one (prefetched) embed row
      const float xe = embed[tok*EE_ + lane];
      float a0 = bias + hacc, a1 = 0.f, a2 = 0.f, a3 = 0.f;
#pragma unroll
      for (int e = 0; e < EE_; e += 4){
        a0 = fmaf(wih[e+0], rlane(xe, e+0), a0);
        a1 = fmaf(wih[e+1], rlane(xe, e+1), a1);
        a2 = fmaf(wih[e+2], rlane(xe, e+2), a2);
        a3 = fmaf(wih[e+3], rlane(xe, e+3), a3);
      }
      sg[t] = (a0 + a1) + (a2 + a3);
      __syncthreads();
      if (t < HH_){
        const float gi = sg[t], gf = sg[128+t], gg = sg[256+t], go = sg[384+t];
        c = sigm(gf)*c + sigm(gi)*tanhf(gg);
        const float hv = sigm(go)*tanhf(c);
        sh[t] = hv;
        __hip_atomic_store((unsigned*)&hq[(size_t)s*BB_*HH_ + b*HH_ + t],
                           __float_as_uint(hv), __ATOMIC_RELAXED, __HIP_MEMORY_SCOPE_AGENT);
      }
      __syncthreads();          // sh ready AND all waves' h stores drained (vmcnt0 at barrier)
      // bump all 8 sentinel REPLICAS in parallel (8 lanes -> 8 distinct lines)
      if (t < 8) astore32(&hsent[(s*8 + t)*32 + b], 1u);
      // overlapped with the mm window: Whh·h for the NEXT step
      const float hacc_n = whh_dot(dWhh + t*HH_, sh[lane], sh[64 + lane]);
      // busy-spin poll of this batch's 200 argmax partials (data IS the sentinel);
      // as each candidate arrives, touch its embed row -> winner is cache-hot.
      unsigned long long m = 0ull;
      if (t < NMM){
        const unsigned long long* pp = part + ((size_t)s*BB_ + b)*NMM + t;
        bool pf = false;
        for (;;){
          if (!m) m = aload64(pp);
          if (m && !pf){
            pf = true;
            const unsigned idx = 0xFFFFFFFFu - (unsigned)(m & 0xFFFFFFFFull);
            const float* er = embed + (size_t)idx*EE_;
            const float p0 = er[0], p1 = er[32];     // both 128B lines of the row
            asm volatile("" :: "v"(p0), "v"(p1));    // keep the touch loads alive
          }
          if (__all(m != 0)) break;
        }
      }
#pragma unroll
      for (int off = 32; off > 0; off >>= 1){
        const unsigned long long o = __shfl_xor(m, off);
        if (o > m) m = o;
      }
      if ((t & 63) == 0) r64[t >> 6] = m;
      __syncthreads();
      if (t == 0){
        unsigned long long best = r64[0];
#pragma unroll
        for (int w = 1; w < 8; ++w) if (r64[w] > best) best = r64[w];
        *stok = (int)(0xFFFFFFFFu - (unsigned)(best & 0xFFFFFFFFull));
      }
      __syncthreads();
      tok = *stok;
      hacc = hacc_n;
    }
  } else {
    // ---------------- matmul workgroup: vocab rows [v0, v0+VW) ----------------
    const int widx = wg - NCELL;
    const int v0 = widx * VW;
    float4* lw4 = (float4*)(smem + OFF_LW);   // [kcc][r]
    float*  lhb = (float*)(smem + OFF_LHB);   // [b][k], stride 128
    float*  rdf = (float*)(smem + OFF_RDF);
    const int ks = t >> 7;          // k-split quarter: k in [ks*32, ks*32+32)
    const int u  = t & 127;
    const int vg = u & 31;          // vocab lane; row v = v0 + vi*32 + vg
    const int bg = u >> 5;          // batch group (8 batches each)
    // stage fc_w slice into LDS once (reused for all 128 steps)
    for (int i = t; i < VW*HH_; i += 512){
      const int r = i >> 7, k = i & 127;
      ((float*)lw4)[((k >> 2)*VW + r)*4 + (k & 3)] = fcw[(size_t)(v0 + r)*HH_ + k];
    }
    float fb[5];
#pragma unroll
    for (int vi = 0; vi < 5; ++vi) fb[vi] = fcb[v0 + vi*32 + vg];
    __syncthreads();
#pragma unroll 1
    for (int s = 0; s < TT_; ++s){
      // busy-spin poll of THIS WG'S sentinel replica line (wave 0 only; 25 pollers/line)
      if (t < 64){
        unsigned v = (t < 32) ? 0u : 1u;
        const unsigned* sl = &hsent[(s*8 + (widx & 7))*32 + t];
        for (;;){
          if (!v) v = aload32(sl);
          if (__all(v != 0)) break;
        }
      }
      __syncthreads();
      // PLAIN cached, coalesced h stage (16KB; per-XCD L2 multicasts across 25 wgs)
      const float4* hsrc = (const float4*)(hq + (size_t)s*BB_*HH_);
#pragma unroll
      for (int i = t; i < BB_*HH_/4; i += 512){
        const float4 v = hsrc[i];
        const int bb = i >> 5, k4 = i & 31;
        *(float4*)&lhb[bb*HH_ + k4*4] = v;
      }
      __syncthreads();
      float acc[5][8];
#pragma unroll
      for (int vi = 0; vi < 5; ++vi)
#pragma unroll
        for (int bi = 0; bi < 8; ++bi) acc[vi][bi] = 0.f;
      const int kb = ks * 8;      // 8 float4-chunks (32 k) per ks
#pragma unroll
      for (int kc = 0; kc < 8; ++kc){
        const int kcc = kb + kc;
        float4 w[5];
#pragma unroll
        for (int vi = 0; vi < 5; ++vi) w[vi] = lw4[kcc*VW + vi*32 + vg];  // read ONCE per kc
#pragma unroll
        for (int bi = 0; bi < 8; ++bi){
          const float4 hb = *(const float4*)&lhb[(bg*8 + bi)*HH_ + kcc*4];  // broadcast read
#pragma unroll
          for (int vi = 0; vi < 5; ++vi)
            acc[vi][bi] = fmaf(w[vi].x,hb.x,fmaf(w[vi].y,hb.y,fmaf(w[vi].z,hb.z,fmaf(w[vi].w,hb.w,acc[vi][bi]))));
        }
      }
      // k-split reduce: ks=1..3 publish, ks=0 combines (stride-41 dwords)
      if (ks){
        float* dst = rdf + ((size_t)(ks-1)*128 + u)*41;
#pragma unroll
        for (int vi = 0; vi < 5; ++vi)
#pragma unroll
          for (int bi = 0; bi < 8; ++bi) dst[vi*8 + bi] = acc[vi][bi];
      }
      __syncthreads();
      if (ks == 0){
#pragma unroll
        for (int r = 0; r < 3; ++r){
          const float* src = rdf + ((size_t)r*128 + u)*41;
#pragma unroll
          for (int vi = 0; vi < 5; ++vi)
#pragma unroll
            for (int bi = 0; bi < 8; ++bi) acc[vi][bi] += src[vi*8 + bi];
        }
#pragma unroll
        for (int vi = 0; vi < 5; ++vi)
#pragma unroll
          for (int bi = 0; bi < 8; ++bi) acc[vi][bi] += fb[vi];
        // per-batch argmax over this wg's 160 rows -> ONE sentinel store per (wg,batch)
#pragma unroll
        for (int bi = 0; bi < 8; ++bi){
          unsigned long long best = 0ull;
#pragma unroll
          for (int vi = 0; vi < 5; ++vi){
            const unsigned long long pk = packmax(acc[vi][bi], v0 + vi*32 + vg);
            if (pk > best) best = pk;
          }
#pragma unroll
          for (int off = 16; off > 0; off >>= 1){
            const unsigned long long o = __shfl_xor(best, off);
            if (o > best) best = o;
          }
          if (vg == 0)
            astore64(&part[((size_t)s*BB_ + bg*8 + bi)*NMM + widx], best);
        }
        // logits after publication (nontemporal; drain during next poll window)
#pragma unroll
        for (int bi = 0; bi < 8; ++bi){
          float* orow = out + ((size_t)(bg*8 + bi)*TT_ + s)*(size_t)VV_ + v0;
#pragma unroll
          for (int vi = 0; vi < 5; ++vi)
            __builtin_nontemporal_store(acc[vi][bi], &orow[vi*32 + vg]);
        }
      }
    }
  }
}

extern "C" void kernel_launch(void* const* d_in, const int* in_sizes, int n_in,
                              void* d_out, int out_size, void* d_ws, size_t ws_size,
                              hipStream_t stream){
  (void)in_sizes; (void)n_in; (void)out_size; (void)ws_size;
  const int*   x     = (const int*)  d_in[0];
  const float* embed = (const float*)d_in[1];
  const float* eWih  = (const float*)d_in[2];
  const float* eWhh  = (const float*)d_in[3];
  const float* eb    = (const float*)d_in[4];
  const float* dWih  = (const float*)d_in[5];
  const float* dWhh  = (const float*)d_in[6];
  const float* db    = (const float*)d_in[7];
  const float* fcw   = (const float*)d_in[8];
  const float* fcb   = (const float*)d_in[9];
  float* out = (float*)d_out;
  char* ws = (char*)d_ws;
  float* hq = (float*)(ws + WS_HQ);
  unsigned long long* part = (unsigned long long*)(ws + WS_PART);
  unsigned* hsent = (unsigned*)(ws + WS_HSENT);
  float* h_enc = (float*)(ws + WS_HENC);
  float* c_enc = (float*)(ws + WS_CENC);

  // zero sentinel/data buffers every launch (graph node -> deterministic replays,
  // clears the harness 0xAA poison which would defeat the sentinels)
  (void)hipMemsetAsync(ws, 0, WS_ZEND, stream);
  // allow >64KB dynamic LDS (gfx950 has 160KB/CU); idempotent host-side call
  (void)hipFuncSetAttribute((const void*)dec_kernel, hipFuncAttributeMaxDynamicSharedMemorySize, DYN_LDS);

  enc_kernel<<<NCELL, 512, 0, stream>>>(x, embed, eWih, eWhh, eb, h_enc, c_enc);
  dec_kernel<<<NWG, 512, DYN_LDS, stream>>>(embed, dWih, dWhh, db, fcw, fcb,
                                            h_enc, c_enc, hq, part, hsent, out);
}

// Round 15
// 1668.837 us; speedup vs baseline: 1.4843x; 1.2746x over previous
//
#include <hip/hip_runtime.h>
#include <math.h>

#define BB_ 32
#define TT_ 128
#define EE_ 64
#define HH_ 128
#define VV_ 32000
#define NMM 200      // matmul workgroups
#define NCELL 32     // cell workgroups (one per batch)
#define NWG (NMM + NCELL)
#define VW 160       // vocab rows per matmul wg (200*160 = 32000)
#define NSREP 64     // h-sentinel line replicas (25 pollers/line)

// ---- dynamic LDS layout (bytes) for matmul wgs ----
#define OFF_LW  0                   // float4[32 kcc][160 r] = 81920  fc_w slice
#define OFF_HSL 81920               // float[8 waves][4 rows][128] = 16384 per-wave h slots
#define DYN_LDS 98304               // 96KB -> 1 wg/CU
// cell wgs overlay (same dynamic buffer, different CUs)
#define OFF_SG  0                   // float[512] gates
#define OFF_SH  2048                // float[128] h
#define OFF_TOK 2560                // int token broadcast
#define OFF_R64 2568                // u64[8] wave argmax partials

// ---- workspace layout (bytes) ----
// h-link: agent-atomic u32 h stores -> LLC; readiness sentinel REPLICATED x64
//         (one 128B line per replica; each mm WAVE polls only ITS 4 batches'
//         words on its replica line); h read with PLAIN CACHED loads.
// part-link: data IS the sentinel (packmax nonzero); reader-contiguous [s][b][widx].
#define WS_HQ    0                                          // f32[TT][BB][HH] = 2,097,152
#define WS_PART  (TT_*BB_*HH_*4)                            // u64[TT][BB][NMM] = 6,553,600
#define WS_HSENT (WS_PART + TT_*BB_*NMM*8)                  // u32[TT][64][32] = 1,048,576
#define WS_ZEND  (WS_HSENT + TT_*NSREP*32*4)                // zero [WS_PART, WS_ZEND)
#define WS_HENC  WS_ZEND                                    // f32[BB*HH]
#define WS_CENC  (WS_HENC + BB_*HH_*4)                      // f32[BB*HH]
#define WS_END   (WS_CENC + BB_*HH_*4)

__device__ __forceinline__ float rlane(float v, int l){
  return __int_as_float(__builtin_amdgcn_readlane(__float_as_int(v), l));
}
__device__ __forceinline__ float sigm(float x){ return 1.f / (1.f + expf(-x)); }

__device__ __forceinline__ unsigned long long packmax(float v, int idx){
  unsigned u = __float_as_uint(v);
  u = (u & 0x80000000u) ? ~u : (u | 0x80000000u);   // monotone float->uint map
  return ((unsigned long long)u << 32) | (unsigned long long)(0xFFFFFFFFu - (unsigned)idx);
}

__device__ __forceinline__ unsigned aload32(const unsigned* p){
  return __hip_atomic_load(p, __ATOMIC_RELAXED, __HIP_MEMORY_SCOPE_AGENT);
}
__device__ __forceinline__ unsigned long long aload64(const unsigned long long* p){
  return __hip_atomic_load(p, __ATOMIC_RELAXED, __HIP_MEMORY_SCOPE_AGENT);
}
__device__ __forceinline__ void astore32(unsigned* p, unsigned v){
  __hip_atomic_store(p, v, __ATOMIC_RELAXED, __HIP_MEMORY_SCOPE_AGENT);
}
__device__ __forceinline__ void astore64(unsigned long long* p, unsigned long long v){
  __hip_atomic_store(p, v, __ATOMIC_RELAXED, __HIP_MEMORY_SCOPE_AGENT);
}

// Whh[row t]·h : 32 float4 L2-stream + readlane broadcasts. Runs in the mm window.
__device__ __forceinline__ float whh_dot(const float* wrow, float h0, float h1){
  const float4* hp = (const float4*)wrow;
  asm volatile("" : "+v"(hp));        // opaque: keep loads inside the loop iteration
  float b0 = 0.f, b1 = 0.f, b2 = 0.f, b3 = 0.f;
#pragma unroll
  for (int q = 0; q < 16; ++q){
    const float4 w = hp[q];
    b0 = fmaf(w.x, rlane(h0, q*4+0), b0);
    b1 = fmaf(w.y, rlane(h0, q*4+1), b1);
    b2 = fmaf(w.z, rlane(h0, q*4+2), b2);
    b3 = fmaf(w.w, rlane(h0, q*4+3), b3);
  }
#pragma unroll
  for (int q = 0; q < 16; ++q){
    const float4 w = hp[16+q];
    b0 = fmaf(w.x, rlane(h1, q*4+0), b0);
    b1 = fmaf(w.y, rlane(h1, q*4+1), b1);
    b2 = fmaf(w.z, rlane(h1, q*4+2), b2);
    b3 = fmaf(w.w, rlane(h1, q*4+3), b3);
  }
  return (b0 + b1) + (b2 + b3);
}

// register-resident full gate dot (encoder)
__device__ __forceinline__ float gate_dot_r(const float (&wih)[EE_], const float (&whh)[HH_],
                                            float bias, float xe, float h0, float h1){
  float a0 = bias, a1 = 0.f, a2 = 0.f, a3 = 0.f;
#pragma unroll
  for (int e = 0; e < EE_; e += 4){
    a0 = fmaf(wih[e+0], rlane(xe, e+0), a0);
    a1 = fmaf(wih[e+1], rlane(xe, e+1), a1);
    a2 = fmaf(wih[e+2], rlane(xe, e+2), a2);
    a3 = fmaf(wih[e+3], rlane(xe, e+3), a3);
  }
#pragma unroll
  for (int j = 0; j < 64; j += 4){
    a0 = fmaf(whh[j+0], rlane(h0, j+0), a0);
    a1 = fmaf(whh[j+1], rlane(h0, j+1), a1);
    a2 = fmaf(whh[j+2], rlane(h0, j+2), a2);
    a3 = fmaf(whh[j+3], rlane(h0, j+3), a3);
  }
#pragma unroll
  for (int j = 0; j < 64; j += 4){
    a0 = fmaf(whh[64+j+0], rlane(h1, j+0), a0);
    a1 = fmaf(whh[64+j+1], rlane(h1, j+1), a1);
    a2 = fmaf(whh[64+j+2], rlane(h1, j+2), a2);
    a3 = fmaf(whh[64+j+3], rlane(h1, j+3), a3);
  }
  return (a0 + a1) + (a2 + a3);
}

// ===================== encoder: 32 wgs (one per batch), no cross-wg deps =====================
__global__ __launch_bounds__(512)
void enc_kernel(const int* __restrict__ xt, const float* __restrict__ embed,
                const float* __restrict__ Wih, const float* __restrict__ Whh,
                const float* __restrict__ bv,
                float* __restrict__ h_out, float* __restrict__ c_out)
{
  const int b = blockIdx.x, t = threadIdx.x, lane = t & 63;
  __shared__ float sh[HH_];
  __shared__ float sg[4*HH_];
  float wih[EE_], whh[HH_];
#pragma unroll
  for (int e = 0; e < EE_; ++e) wih[e] = Wih[t*EE_ + e];
#pragma unroll
  for (int j = 0; j < HH_; ++j) whh[j] = Whh[t*HH_ + j];
  const float bias = bv[t];
  float c = 0.f, hv = 0.f;
  if (t < HH_) sh[t] = 0.f;
  __syncthreads();
#pragma unroll 1
  for (int s = 0; s < TT_; ++s){
    const int tok = xt[b*TT_ + s];
    const float xe = embed[tok*EE_ + lane];
    const float h0 = sh[lane], h1 = sh[64 + lane];
    const float g = gate_dot_r(wih, whh, bias, xe, h0, h1);
    __syncthreads();   // all sh reads done
    sg[t] = g;
    __syncthreads();
    if (t < HH_){
      const float gi = sg[t], gf = sg[128+t], gg = sg[256+t], go = sg[384+t];
      c = sigm(gf)*c + sigm(gi)*tanhf(gg);
      hv = sigm(go)*tanhf(c);
      sh[t] = hv;
    }
    __syncthreads();
  }
  if (t < HH_){ h_out[b*HH_ + t] = hv; c_out[b*HH_ + t] = c; }
}

// ===================== decoder: persistent, 32 cell wgs + 200 matmul wgs =====================
__global__ __launch_bounds__(512)
void dec_kernel(const float* __restrict__ embed,
                const float* __restrict__ dWih, const float* __restrict__ dWhh,
                const float* __restrict__ db,
                const float* __restrict__ fcw, const float* __restrict__ fcb,
                const float* __restrict__ h_enc, const float* __restrict__ c_enc,
                float* __restrict__ hq, unsigned long long* __restrict__ part,
                unsigned* __restrict__ hsent, float* __restrict__ out)
{
  extern __shared__ char smem[];
  const int t = threadIdx.x;
  const int wg = blockIdx.x;

  if (wg < NCELL){
    // ---------------- cell workgroup: owns batch b (pipelined gate) ----------------
    float* sg = (float*)(smem + OFF_SG);
    float* sh = (float*)(smem + OFF_SH);
    int* stok = (int*)(smem + OFF_TOK);
    unsigned long long* r64 = (unsigned long long*)(smem + OFF_R64);
    const int b = wg, lane = t & 63;
    const float bias = db[t];
    float wih[EE_];                       // x-part weights live in REGISTERS
#pragma unroll
    for (int e = 0; e < EE_; ++e) wih[e] = dWih[t*EE_ + e];
    float c = 0.f;
    if (t < HH_){ c = c_enc[b*HH_ + t]; sh[t] = h_enc[b*HH_ + t]; }
    int tok = 1; // SOS
    __syncthreads();
    // Whh·h for the first step (h_enc), off the critical chain
    float hacc = whh_dot(dWhh + t*HH_, sh[lane], sh[64 + lane]);
#pragma unroll 1
    for (int s = 0; s < TT_; ++s){
      // token-dependent part only: 64 reg-FMAs + one (prefetched) embed row
      const float xe = embed[tok*EE_ + lane];
      float a0 = bias + hacc, a1 = 0.f, a2 = 0.f, a3 = 0.f;
#pragma unroll
      for (int e = 0; e < EE_; e += 4){
        a0 = fmaf(wih[e+0], rlane(xe, e+0), a0);
        a1 = fmaf(wih[e+1], rlane(xe, e+1), a1);
        a2 = fmaf(wih[e+2], rlane(xe, e+2), a2);
        a3 = fmaf(wih[e+3], rlane(xe, e+3), a3);
      }
      sg[t] = (a0 + a1) + (a2 + a3);
      __syncthreads();
      if (t < HH_){
        const float gi = sg[t], gf = sg[128+t], gg = sg[256+t], go = sg[384+t];
        c = sigm(gf)*c + sigm(gi)*tanhf(gg);
        const float hv = sigm(go)*tanhf(c);
        sh[t] = hv;
        __hip_atomic_store((unsigned*)&hq[(size_t)s*BB_*HH_ + b*HH_ + t],
                           __float_as_uint(hv), __ATOMIC_RELAXED, __HIP_MEMORY_SCOPE_AGENT);
      }
      __syncthreads();          // sh ready AND all waves' h stores drained (vmcnt0 at barrier)
      // bump all 64 sentinel REPLICAS in parallel (one scatter instr, 64 distinct lines)
      if (t < NSREP) astore32(&hsent[((size_t)s*NSREP + t)*32 + b], 1u);
      // overlapped with the mm window: Whh·h for the NEXT step
      const float hacc_n = whh_dot(dWhh + t*HH_, sh[lane], sh[64 + lane]);
      // busy-spin poll of this batch's 200 argmax partials (data IS the sentinel);
      // as each candidate arrives, touch its embed row -> winner is cache-hot.
      unsigned long long m = 0ull;
      if (t < NMM){
        const unsigned long long* pp = part + ((size_t)s*BB_ + b)*NMM + t;
        bool pf = false;
        for (;;){
          if (!m) m = aload64(pp);
          if (m && !pf){
            pf = true;
            const unsigned idx = 0xFFFFFFFFu - (unsigned)(m & 0xFFFFFFFFull);
            const float* er = embed + (size_t)idx*EE_;
            const float p0 = er[0], p1 = er[32];     // both 128B lines of the row
            asm volatile("" :: "v"(p0), "v"(p1));    // keep the touch loads alive
          }
          if (__all(m != 0)) break;
        }
      }
#pragma unroll
      for (int off = 32; off > 0; off >>= 1){
        const unsigned long long o = __shfl_xor(m, off);
        if (o > m) m = o;
      }
      if ((t & 63) == 0) r64[t >> 6] = m;
      __syncthreads();
      if (t == 0){
        unsigned long long best = r64[0];
#pragma unroll
        for (int w = 1; w < 8; ++w) if (r64[w] > best) best = r64[w];
        *stok = (int)(0xFFFFFFFFu - (unsigned)(best & 0xFFFFFFFFull));
      }
      __syncthreads();
      tok = *stok;
      hacc = hacc_n;
    }
  } else {
    // -------- matmul workgroup: vocab rows [v0, v0+VW), WAVE-AUTONOMOUS steps --------
    // thread map: vg = t&31 (vocab lane), bh = (t>>5)&1, wv = t>>6 (wave 0..7)
    // wave wv owns batches {2wv, 2wv+1, 2wv+16, 2wv+17}; thread covers
    // b0 = 2wv+bh and b1 = b0+16 with FULL K=128 (no k-split, no reduce, no barriers).
    const int widx = wg - NCELL;
    const int v0 = widx * VW;
    float4* lw4 = (float4*)(smem + OFF_LW);   // [kcc 0..31][160 r]
    float*  hsl = (float*)(smem + OFF_HSL);   // [8 waves][4 rows][128]
    const int vg = t & 31;
    const int bh = (t >> 5) & 1;
    const int wv = t >> 6;
    const int lane = t & 63;
    const int lr0 = bh, lr1 = bh + 2;         // local slot rows for b0, b1
    float* myslot = hsl + wv*4*HH_;
    // stage fc_w slice into LDS once (reused for all 128 steps)
    for (int i = t; i < VW*HH_; i += 512){
      const int r = i >> 7, k = i & 127;
      ((float*)lw4)[((k >> 2)*VW + r)*4 + (k & 3)] = fcw[(size_t)(v0 + r)*HH_ + k];
    }
    float fb[5];
#pragma unroll
    for (int vi = 0; vi < 5; ++vi) fb[vi] = fcb[v0 + vi*32 + vg];
    __syncthreads();                          // the ONLY wg barrier (fc_w ready)
#pragma unroll 1
    for (int s = 0; s < TT_; ++s){
      // per-wave poll: 4 lanes watch THIS WAVE'S 4 batches on its replica line
      {
        const int rep = (widx*8 + wv) & (NSREP - 1);
        const unsigned* line = &hsent[((size_t)s*NSREP + rep)*32];
        unsigned v = 1u;
        int wb = 0;
        if (lane < 4){ v = 0u; wb = 2*wv + (lane & 1) + ((lane >> 1) ? 16 : 0); }
        for (;;){
          if (!v) v = aload32(&line[wb]);
          if (__all(v != 0)) break;
        }
      }
      // wave-local h load: 4 rows x 128 floats -> this wave's LDS slot
      {
        const int row = lane >> 4;            // 0..3
        const int gb  = 2*wv + (row & 1) + ((row >> 1) ? 16 : 0);
        const float4* src = (const float4*)(hq + (size_t)s*BB_*HH_ + gb*HH_);
        const int c0 = (lane & 15) * 2;
        const float4 va = src[c0], vb = src[c0+1];
        float4* dst = (float4*)(myslot + row*HH_);
        dst[c0] = va; dst[c0+1] = vb;
        asm volatile("s_waitcnt lgkmcnt(0)" ::: "memory");   // wave-sync LDS visibility
        __builtin_amdgcn_sched_barrier(0);
      }
      float acc[5][2];
#pragma unroll
      for (int vi = 0; vi < 5; ++vi){ acc[vi][0] = 0.f; acc[vi][1] = 0.f; }
#pragma unroll 4
      for (int kcc = 0; kcc < 32; ++kcc){
        const float4 hb0 = *(const float4*)&myslot[lr0*HH_ + kcc*4];  // broadcast
        const float4 hb1 = *(const float4*)&myslot[lr1*HH_ + kcc*4];  // broadcast
#pragma unroll
        for (int vi = 0; vi < 5; ++vi){
          const float4 w = lw4[kcc*VW + vi*32 + vg];
          acc[vi][0] = fmaf(w.x,hb0.x,fmaf(w.y,hb0.y,fmaf(w.z,hb0.z,fmaf(w.w,hb0.w,acc[vi][0]))));
          acc[vi][1] = fmaf(w.x,hb1.x,fmaf(w.y,hb1.y,fmaf(w.z,hb1.z,fmaf(w.w,hb1.w,acc[vi][1]))));
        }
      }
#pragma unroll
      for (int vi = 0; vi < 5; ++vi){ acc[vi][0] += fb[vi]; acc[vi][1] += fb[vi]; }
      const int b0 = 2*wv + bh, b1 = b0 + 16;
      // per-batch argmax over this wave's 160 rows -> ONE sentinel store per (wg,batch)
#pragma unroll
      for (int bi = 0; bi < 2; ++bi){
        unsigned long long best = 0ull;
#pragma unroll
        for (int vi = 0; vi < 5; ++vi){
          const unsigned long long pk = packmax(acc[vi][bi], v0 + vi*32 + vg);
          if (pk > best) best = pk;
        }
#pragma unroll
        for (int off = 16; off > 0; off >>= 1){     // butterfly within the 32-lane group
          const unsigned long long o = __shfl_xor(best, off);
          if (o > best) best = o;
        }
        if (vg == 0)
          astore64(&part[((size_t)s*BB_ + (bi ? b1 : b0))*NMM + widx], best);
      }
      // logits after publication (nontemporal; drain during next poll window)
      {
        float* orow0 = out + ((size_t)b0*TT_ + s)*(size_t)VV_ + v0;
        float* orow1 = out + ((size_t)b1*TT_ + s)*(size_t)VV_ + v0;
#pragma unroll
        for (int vi = 0; vi < 5; ++vi){
          __builtin_nontemporal_store(acc[vi][0], &orow0[vi*32 + vg]);
          __builtin_nontemporal_store(acc[vi][1], &orow1[vi*32 + vg]);
        }
      }
    }
  }
}

extern "C" void kernel_launch(void* const* d_in, const int* in_sizes, int n_in,
                              void* d_out, int out_size, void* d_ws, size_t ws_size,
                              hipStream_t stream){
  (void)in_sizes; (void)n_in; (void)out_size; (void)ws_size;
  const int*   x     = (const int*)  d_in[0];
  const float* embed = (const float*)d_in[1];
  const float* eWih  = (const float*)d_in[2];
  const float* eWhh  = (const float*)d_in[3];
  const float* eb    = (const float*)d_in[4];
  const float* dWih  = (const float*)d_in[5];
  const float* dWhh  = (const float*)d_in[6];
  const float* db    = (const float*)d_in[7];
  const float* fcw   = (const float*)d_in[8];
  const float* fcb   = (const float*)d_in[9];
  float* out = (float*)d_out;
  char* ws = (char*)d_ws;
  float* hq = (float*)(ws + WS_HQ);
  unsigned long long* part = (unsigned long long*)(ws + WS_PART);
  unsigned* hsent = (unsigned*)(ws + WS_HSENT);
  float* h_enc = (float*)(ws + WS_HENC);
  float* c_enc = (float*)(ws + WS_CENC);

  // zero the sentinel surfaces (part, hsent) each launch (graph node ->
  // deterministic replays; clears the harness 0xAA poison which would defeat
  // the sentinels). hq needs no clearing: reads are gated by hsent.
  (void)hipMemsetAsync(ws + WS_PART, 0, WS_ZEND - WS_PART, stream);
  // allow >64KB dynamic LDS (gfx950 has 160KB/CU); idempotent host-side call
  (void)hipFuncSetAttribute((const void*)dec_kernel, hipFuncAttributeMaxDynamicSharedMemorySize, DYN_LDS);

  enc_kernel<<<NCELL, 512, 0, stream>>>(x, embed, eWih, eWhh, eb, h_enc, c_enc);
  dec_kernel<<<NWG, 512, DYN_LDS, stream>>>(embed, dWih, dWhh, db, fcw, fcb,
                                            h_enc, c_enc, hq, part, hsent, out);
}

// Round 16
// 1618.269 us; speedup vs baseline: 1.5307x; 1.0312x over previous
//
#include <hip/hip_runtime.h>
#include <math.h>

#define BB_ 32
#define TT_ 128
#define EE_ 64
#define HH_ 128
#define VV_ 32000
#define NMM 200      // matmul workgroups
#define NCELL 32     // cell workgroups (one per batch)
#define NWG (NMM + NCELL)
#define VW 160       // vocab rows per matmul wg (200*160 = 32000)

// ---- dynamic LDS layout (bytes) for matmul wgs ----
#define OFF_LW  0                   // float4[32 kcc][160 r] = 81920  fc_w slice
#define OFF_HSL 81920               // float[8 waves][4 rows][128] = 16384 per-wave h slots
#define DYN_LDS 98304               // 96KB -> 1 wg/CU
// cell wgs overlay (same dynamic buffer, different CUs)
#define OFF_SG  0                   // float[512] gates
#define OFF_SH  2048                // float[128] h
#define OFF_TOK 2560                // int token broadcast
#define OFF_R64 2568                // u64[8] wave argmax partials

// ---- workspace layout (bytes) ----
// h-link: DATA IS THE SENTINEL. Cell packs (h+2.0) pairs -> u64 (bits never 0
//         since h+2 in (1,3)); each mm WAVE polls its own 4-batch 2KB block
//         directly with uncached atomic u64 loads -> data in regs at detect,
//         no second hop. (R9 encoding + R15 wave autonomy.)
// part-link: data IS the sentinel (packmax nonzero); reader-contiguous [s][b][widx].
#define WS_HQ    0                                          // u64[TT][BB][64] = 2,097,152
#define WS_PART  (TT_*BB_*64*8)                             // u64[TT][BB][NMM] = 6,553,600
#define WS_ZEND  (WS_PART + (size_t)TT_*BB_*NMM*8)          // zero [0, WS_ZEND) each launch
#define WS_HENC  WS_ZEND                                    // f32[BB*HH]
#define WS_CENC  (WS_HENC + BB_*HH_*4)                      // f32[BB*HH]
#define WS_END   (WS_CENC + BB_*HH_*4)

__device__ __forceinline__ float rlane(float v, int l){
  return __int_as_float(__builtin_amdgcn_readlane(__float_as_int(v), l));
}
__device__ __forceinline__ float sigm(float x){ return 1.f / (1.f + expf(-x)); }

__device__ __forceinline__ unsigned long long packmax(float v, int idx){
  unsigned u = __float_as_uint(v);
  u = (u & 0x80000000u) ? ~u : (u | 0x80000000u);   // monotone float->uint map
  return ((unsigned long long)u << 32) | (unsigned long long)(0xFFFFFFFFu - (unsigned)idx);
}

__device__ __forceinline__ unsigned long long aload64(const unsigned long long* p){
  return __hip_atomic_load(p, __ATOMIC_RELAXED, __HIP_MEMORY_SCOPE_AGENT);
}
__device__ __forceinline__ void astore64(unsigned long long* p, unsigned long long v){
  __hip_atomic_store(p, v, __ATOMIC_RELAXED, __HIP_MEMORY_SCOPE_AGENT);
}

// Whh[row t]·h : 32 float4 L2-stream + readlane broadcasts. Runs in the mm window.
__device__ __forceinline__ float whh_dot(const float* wrow, float h0, float h1){
  const float4* hp = (const float4*)wrow;
  asm volatile("" : "+v"(hp));        // opaque: keep loads inside the loop iteration
  float b0 = 0.f, b1 = 0.f, b2 = 0.f, b3 = 0.f;
#pragma unroll
  for (int q = 0; q < 16; ++q){
    const float4 w = hp[q];
    b0 = fmaf(w.x, rlane(h0, q*4+0), b0);
    b1 = fmaf(w.y, rlane(h0, q*4+1), b1);
    b2 = fmaf(w.z, rlane(h0, q*4+2), b2);
    b3 = fmaf(w.w, rlane(h0, q*4+3), b3);
  }
#pragma unroll
  for (int q = 0; q < 16; ++q){
    const float4 w = hp[16+q];
    b0 = fmaf(w.x, rlane(h1, q*4+0), b0);
    b1 = fmaf(w.y, rlane(h1, q*4+1), b1);
    b2 = fmaf(w.z, rlane(h1, q*4+2), b2);
    b3 = fmaf(w.w, rlane(h1, q*4+3), b3);
  }
  return (b0 + b1) + (b2 + b3);
}

// register-resident full gate dot (encoder)
__device__ __forceinline__ float gate_dot_r(const float (&wih)[EE_], const float (&whh)[HH_],
                                            float bias, float xe, float h0, float h1){
  float a0 = bias, a1 = 0.f, a2 = 0.f, a3 = 0.f;
#pragma unroll
  for (int e = 0; e < EE_; e += 4){
    a0 = fmaf(wih[e+0], rlane(xe, e+0), a0);
    a1 = fmaf(wih[e+1], rlane(xe, e+1), a1);
    a2 = fmaf(wih[e+2], rlane(xe, e+2), a2);
    a3 = fmaf(wih[e+3], rlane(xe, e+3), a3);
  }
#pragma unroll
  for (int j = 0; j < 64; j += 4){
    a0 = fmaf(whh[j+0], rlane(h0, j+0), a0);
    a1 = fmaf(whh[j+1], rlane(h0, j+1), a1);
    a2 = fmaf(whh[j+2], rlane(h0, j+2), a2);
    a3 = fmaf(whh[j+3], rlane(h0, j+3), a3);
  }
#pragma unroll
  for (int j = 0; j < 64; j += 4){
    a0 = fmaf(whh[64+j+0], rlane(h1, j+0), a0);
    a1 = fmaf(whh[64+j+1], rlane(h1, j+1), a1);
    a2 = fmaf(whh[64+j+2], rlane(h1, j+2), a2);
    a3 = fmaf(whh[64+j+3], rlane(h1, j+3), a3);
  }
  return (a0 + a1) + (a2 + a3);
}

// ===================== encoder: 32 wgs (one per batch), no cross-wg deps =====================
__global__ __launch_bounds__(512)
void enc_kernel(const int* __restrict__ xt, const float* __restrict__ embed,
                const float* __restrict__ Wih, const float* __restrict__ Whh,
                const float* __restrict__ bv,
                float* __restrict__ h_out, float* __restrict__ c_out)
{
  const int b = blockIdx.x, t = threadIdx.x, lane = t & 63;
  __shared__ float sh[HH_];
  __shared__ float sg[4*HH_];
  float wih[EE_], whh[HH_];
#pragma unroll
  for (int e = 0; e < EE_; ++e) wih[e] = Wih[t*EE_ + e];
#pragma unroll
  for (int j = 0; j < HH_; ++j) whh[j] = Whh[t*HH_ + j];
  const float bias = bv[t];
  float c = 0.f, hv = 0.f;
  if (t < HH_) sh[t] = 0.f;
  __syncthreads();
#pragma unroll 1
  for (int s = 0; s < TT_; ++s){
    const int tok = xt[b*TT_ + s];
    const float xe = embed[tok*EE_ + lane];
    const float h0 = sh[lane], h1 = sh[64 + lane];
    const float g = gate_dot_r(wih, whh, bias, xe, h0, h1);
    __syncthreads();   // all sh reads done
    sg[t] = g;
    __syncthreads();
    if (t < HH_){
      const float gi = sg[t], gf = sg[128+t], gg = sg[256+t], go = sg[384+t];
      c = sigm(gf)*c + sigm(gi)*tanhf(gg);
      hv = sigm(go)*tanhf(c);
      sh[t] = hv;
    }
    __syncthreads();
  }
  if (t < HH_){ h_out[b*HH_ + t] = hv; c_out[b*HH_ + t] = c; }
}

// ===================== decoder: persistent, 32 cell wgs + 200 matmul wgs =====================
__global__ __launch_bounds__(512)
void dec_kernel(const float* __restrict__ embed,
                const float* __restrict__ dWih, const float* __restrict__ dWhh,
                const float* __restrict__ db,
                const float* __restrict__ fcw, const float* __restrict__ fcb,
                const float* __restrict__ h_enc, const float* __restrict__ c_enc,
                unsigned long long* __restrict__ hq, unsigned long long* __restrict__ part,
                float* __restrict__ out)
{
  extern __shared__ char smem[];
  const int t = threadIdx.x;
  const int wg = blockIdx.x;

  if (wg < NCELL){
    // ---------------- cell workgroup: owns batch b (pipelined gate) ----------------
    float* sg = (float*)(smem + OFF_SG);
    float* sh = (float*)(smem + OFF_SH);
    int* stok = (int*)(smem + OFF_TOK);
    unsigned long long* r64 = (unsigned long long*)(smem + OFF_R64);
    const int b = wg, lane = t & 63;
    const float bias = db[t];
    float wih[EE_];                       // x-part weights live in REGISTERS
#pragma unroll
    for (int e = 0; e < EE_; ++e) wih[e] = dWih[t*EE_ + e];
    float c = 0.f;
    if (t < HH_){ c = c_enc[b*HH_ + t]; sh[t] = h_enc[b*HH_ + t]; }
    int tok = 1; // SOS
    __syncthreads();
    // Whh·h for the first step (h_enc), off the critical chain
    float hacc = whh_dot(dWhh + t*HH_, sh[lane], sh[64 + lane]);
#pragma unroll 1
    for (int s = 0; s < TT_; ++s){
      // token-dependent part only: 64 reg-FMAs + one (prefetched) embed row
      const float xe = embed[tok*EE_ + lane];
      float a0 = bias + hacc, a1 = 0.f, a2 = 0.f, a3 = 0.f;
#pragma unroll
      for (int e = 0; e < EE_; e += 4){
        a0 = fmaf(wih[e+0], rlane(xe, e+0), a0);
        a1 = fmaf(wih[e+1], rlane(xe, e+1), a1);
        a2 = fmaf(wih[e+2], rlane(xe, e+2), a2);
        a3 = fmaf(wih[e+3], rlane(xe, e+3), a3);
      }
      sg[t] = (a0 + a1) + (a2 + a3);
      __syncthreads();
      if (t < HH_){
        const float gi = sg[t], gf = sg[128+t], gg = sg[256+t], go = sg[384+t];
        c = sigm(gf)*c + sigm(gi)*tanhf(gg);
        const float hv = sigm(go)*tanhf(c);
        sh[t] = hv;
        // publish h AS SENTINEL DATA: (h+2) in (1,3), bits never zero.
        // pair even/odd lanes via shfl -> one u64 store per even lane.
        const float hp2 = hv + 2.0f;
        const float pr  = __shfl_xor(hp2, 1);
        if (!(t & 1))
          astore64(&hq[(size_t)s*BB_*64 + b*64 + (t >> 1)],
                   (unsigned long long)__float_as_uint(hp2) |
                   ((unsigned long long)__float_as_uint(pr) << 32));
      }
      __syncthreads();          // sh ready for whh_dot (stores drain in flight)
      // overlapped with the mm window: Whh·h for the NEXT step
      const float hacc_n = whh_dot(dWhh + t*HH_, sh[lane], sh[64 + lane]);
      // busy-spin poll of this batch's 200 argmax partials (data IS the sentinel);
      // as each candidate arrives, touch its embed row -> winner is cache-hot.
      unsigned long long m = 0ull;
      if (t < NMM){
        const unsigned long long* pp = part + ((size_t)s*BB_ + b)*NMM + t;
        bool pf = false;
        for (;;){
          if (!m) m = aload64(pp);
          if (m && !pf){
            pf = true;
            const unsigned idx = 0xFFFFFFFFu - (unsigned)(m & 0xFFFFFFFFull);
            const float* er = embed + (size_t)idx*EE_;
            const float p0 = er[0], p1 = er[32];     // both 128B lines of the row
            asm volatile("" :: "v"(p0), "v"(p1));    // keep the touch loads alive
          }
          if (__all(m != 0)) break;
        }
      }
#pragma unroll
      for (int off = 32; off > 0; off >>= 1){
        const unsigned long long o = __shfl_xor(m, off);
        if (o > m) m = o;
      }
      if ((t & 63) == 0) r64[t >> 6] = m;
      __syncthreads();
      if (t == 0){
        unsigned long long best = r64[0];
#pragma unroll
        for (int w = 1; w < 8; ++w) if (r64[w] > best) best = r64[w];
        *stok = (int)(0xFFFFFFFFu - (unsigned)(best & 0xFFFFFFFFull));
      }
      __syncthreads();
      tok = *stok;
      hacc = hacc_n;
    }
  } else {
    // -------- matmul workgroup: vocab rows [v0, v0+VW), WAVE-AUTONOMOUS steps --------
    // thread map: vg = t&31 (vocab lane), bh = (t>>5)&1, wv = t>>6 (wave 0..7)
    // wave wv owns batches {2wv, 2wv+1, 2wv+16, 2wv+17}; thread covers
    // b0 = 2wv+bh and b1 = b0+16 with FULL K=128 (no k-split, no barriers).
    const int widx = wg - NCELL;
    const int v0 = widx * VW;
    float4* lw4 = (float4*)(smem + OFF_LW);   // [kcc 0..31][160 r]
    float*  hsl = (float*)(smem + OFF_HSL);   // [8 waves][4 rows][128]
    const int vg = t & 31;
    const int bh = (t >> 5) & 1;
    const int wv = t >> 6;
    const int lane = t & 63;
    const int lr0 = bh, lr1 = bh + 2;         // local slot rows for b0, b1
    float* myslot = hsl + wv*4*HH_;
    // stage fc_w slice into LDS once (reused for all 128 steps)
    for (int i = t; i < VW*HH_; i += 512){
      const int r = i >> 7, k = i & 127;
      ((float*)lw4)[((k >> 2)*VW + r)*4 + (k & 3)] = fcw[(size_t)(v0 + r)*HH_ + k];
    }
    float fb[5];
#pragma unroll
    for (int vi = 0; vi < 5; ++vi) fb[vi] = fcb[v0 + vi*32 + vg];
    __syncthreads();                          // the ONLY wg barrier (fc_w ready)
#pragma unroll 1
    for (int s = 0; s < TT_; ++s){
      // per-wave DATA-POLL of this wave's 4 batches (sentinel-encoded h+2):
      // lane covers u64 words [4*(lane&15) .. +4) of slot row lane>>4.
      {
        const int row = lane >> 4;            // 0..3
        const int gb  = 2*wv + (row & 1) + ((row >> 1) ? 16 : 0);
        const unsigned long long* pp = hq + (size_t)s*BB_*64 + gb*64 + (lane & 15)*4;
        unsigned long long g0 = 0, g1 = 0, g2 = 0, g3 = 0;
        for (;;){
          if (!g0) g0 = aload64(pp + 0);
          if (!g1) g1 = aload64(pp + 1);
          if (!g2) g2 = aload64(pp + 2);
          if (!g3) g3 = aload64(pp + 3);
          if (__all(g0 && g1 && g2 && g3)) break;
        }
        // unpack (subtract sentinel bias) into this wave's LDS slot
        float2 f0, f1, f2, f3;
        f0.x = __uint_as_float((unsigned)g0) - 2.0f; f0.y = __uint_as_float((unsigned)(g0>>32)) - 2.0f;
        f1.x = __uint_as_float((unsigned)g1) - 2.0f; f1.y = __uint_as_float((unsigned)(g1>>32)) - 2.0f;
        f2.x = __uint_as_float((unsigned)g2) - 2.0f; f2.y = __uint_as_float((unsigned)(g2>>32)) - 2.0f;
        f3.x = __uint_as_float((unsigned)g3) - 2.0f; f3.y = __uint_as_float((unsigned)(g3>>32)) - 2.0f;
        float* dst = myslot + row*HH_ + (lane & 15)*8;
        *(float2*)(dst+0) = f0; *(float2*)(dst+2) = f1;
        *(float2*)(dst+4) = f2; *(float2*)(dst+6) = f3;
        asm volatile("s_waitcnt lgkmcnt(0)" ::: "memory");   // wave-sync LDS visibility
        __builtin_amdgcn_sched_barrier(0);
      }
      float acc[5][2];
#pragma unroll
      for (int vi = 0; vi < 5; ++vi){ acc[vi][0] = 0.f; acc[vi][1] = 0.f; }
#pragma unroll 4
      for (int kcc = 0; kcc < 32; ++kcc){
        const float4 hb0 = *(const float4*)&myslot[lr0*HH_ + kcc*4];  // broadcast
        const float4 hb1 = *(const float4*)&myslot[lr1*HH_ + kcc*4];  // broadcast
#pragma unroll
        for (int vi = 0; vi < 5; ++vi){
          const float4 w = lw4[kcc*VW + vi*32 + vg];
          acc[vi][0] = fmaf(w.x,hb0.x,fmaf(w.y,hb0.y,fmaf(w.z,hb0.z,fmaf(w.w,hb0.w,acc[vi][0]))));
          acc[vi][1] = fmaf(w.x,hb1.x,fmaf(w.y,hb1.y,fmaf(w.z,hb1.z,fmaf(w.w,hb1.w,acc[vi][1]))));
        }
      }
#pragma unroll
      for (int vi = 0; vi < 5; ++vi){ acc[vi][0] += fb[vi]; acc[vi][1] += fb[vi]; }
      const int b0 = 2*wv + bh, b1 = b0 + 16;
      // per-batch argmax over this wave's 160 rows -> ONE sentinel store per (wg,batch)
#pragma unroll
      for (int bi = 0; bi < 2; ++bi){
        unsigned long long best = 0ull;
#pragma unroll
        for (int vi = 0; vi < 5; ++vi){
          const unsigned long long pk = packmax(acc[vi][bi], v0 + vi*32 + vg);
          if (pk > best) best = pk;
        }
#pragma unroll
        for (int off = 16; off > 0; off >>= 1){     // butterfly within the 32-lane group
          const unsigned long long o = __shfl_xor(best, off);
          if (o > best) best = o;
        }
        if (vg == 0)
          astore64(&part[((size_t)s*BB_ + (bi ? b1 : b0))*NMM + widx], best);
      }
      // logits after publication (nontemporal; drain during next poll window)
      {
        float* orow0 = out + ((size_t)b0*TT_ + s)*(size_t)VV_ + v0;
        float* orow1 = out + ((size_t)b1*TT_ + s)*(size_t)VV_ + v0;
#pragma unroll
        for (int vi = 0; vi < 5; ++vi){
          __builtin_nontemporal_store(acc[vi][0], &orow0[vi*32 + vg]);
          __builtin_nontemporal_store(acc[vi][1], &orow1[vi*32 + vg]);
        }
      }
    }
  }
}

extern "C" void kernel_launch(void* const* d_in, const int* in_sizes, int n_in,
                              void* d_out, int out_size, void* d_ws, size_t ws_size,
                              hipStream_t stream){
  (void)in_sizes; (void)n_in; (void)out_size; (void)ws_size;
  const int*   x     = (const int*)  d_in[0];
  const float* embed = (const float*)d_in[1];
  const float* eWih  = (const float*)d_in[2];
  const float* eWhh  = (const float*)d_in[3];
  const float* eb    = (const float*)d_in[4];
  const float* dWih  = (const float*)d_in[5];
  const float* dWhh  = (const float*)d_in[6];
  const float* db    = (const float*)d_in[7];
  const float* fcw   = (const float*)d_in[8];
  const float* fcb   = (const float*)d_in[9];
  float* out = (float*)d_out;
  char* ws = (char*)d_ws;
  unsigned long long* hq   = (unsigned long long*)(ws + WS_HQ);
  unsigned long long* part = (unsigned long long*)(ws + WS_PART);
  float* h_enc = (float*)(ws + WS_HENC);
  float* c_enc = (float*)(ws + WS_CENC);

  // zero BOTH sentinel surfaces (hq data-sentinels + part) each launch
  // (graph node -> deterministic replays; clears the harness 0xAA poison)
  (void)hipMemsetAsync(ws, 0, WS_ZEND, stream);
  // allow >64KB dynamic LDS (gfx950 has 160KB/CU); idempotent host-side call
  (void)hipFuncSetAttribute((const void*)dec_kernel, hipFuncAttributeMaxDynamicSharedMemorySize, DYN_LDS);

  enc_kernel<<<NCELL, 512, 0, stream>>>(x, embed, eWih, eWhh, eb, h_enc, c_enc);
  dec_kernel<<<NWG, 512, DYN_LDS, stream>>>(embed, dWih, dWhh, db, fcw, fcb,
                                            h_enc, c_enc, hq, part, out);
}